// Round 9
// baseline (121.041 us; speedup 1.0000x reference)
//
#include <hip/hip_runtime.h>

#define B_DIM 4096
#define T_DIM 16384
#define WAVES_PER_BLOCK 4
#define CHUNK 256              // samples per wave per iteration (64 lanes * 4)
#define NIT (T_DIM / CHUNK)    // 64

typedef float f32x4 __attribute__((ext_vector_type(4)));

struct M2 { float a, b, c, d; };  // [[a,b],[c,d]]

__device__ inline M2 m2mul(const M2& X, const M2& Y) {
    M2 r;
    r.a = fmaf(X.a, Y.a, X.b * Y.c);
    r.b = fmaf(X.a, Y.b, X.b * Y.d);
    r.c = fmaf(X.c, Y.a, X.d * Y.c);
    r.d = fmaf(X.c, Y.b, X.d * Y.d);
    return r;
}

__global__ __launch_bounds__(256) void biquad_scan_kernel(
    const float* __restrict__ x, const float* __restrict__ v0in,
    const float* __restrict__ pb0, const float* __restrict__ pb1,
    const float* __restrict__ pb2, const float* __restrict__ pa1,
    const float* __restrict__ pa2,
    float* __restrict__ y, float* __restrict__ vout)
{
    const int lane = threadIdx.x & 63;
    const int wave = threadIdx.x >> 6;
    const int row  = blockIdx.x * WAVES_PER_BLOCK + wave;
    if (row >= B_DIM) return;

    const float b0 = *pb0, b1 = *pb1, b2 = *pb2, a1 = *pa1, a2 = *pa2;
    const float na1 = -a1, na2 = -a2;
    const float c0 = b1 - a1 * b0;   // state-update input coeffs
    const float c1 = b2 - a2 * b0;

    // A = [[-a1, 1], [-a2, 0]]
    M2 A  { na1, 1.0f, na2, 0.0f };
    M2 A2 = m2mul(A, A);
    M2 A4 = m2mul(A2, A2);

    // S[s] = A^(4*2^s) scan matrices; Q = A^(4*lane); R = A^256.
    M2 S0, S1, S2, S3, S4, S5;
    M2 Q { 1.f, 0.f, 0.f, 1.f };
    M2 M = A4;
    S0 = M; if (lane & 1)  Q = m2mul(M, Q); M = m2mul(M, M);
    S1 = M; if (lane & 2)  Q = m2mul(M, Q); M = m2mul(M, M);
    S2 = M; if (lane & 4)  Q = m2mul(M, Q); M = m2mul(M, M);
    S3 = M; if (lane & 8)  Q = m2mul(M, Q); M = m2mul(M, M);
    S4 = M; if (lane & 16) Q = m2mul(M, Q); M = m2mul(M, M);
    S5 = M; if (lane & 32) Q = m2mul(M, Q); M = m2mul(M, M);
    const M2 R = M;  // A^256

    const float* xr = x + (size_t)row * T_DIM;
    float*       yr = y + (size_t)row * T_DIM;

    float vc0 = v0in[row * 2 + 0];
    float vc1 = v0in[row * 2 + 1];

    const f32x4* xp = (const f32x4*)xr;
    f32x4*       yp = (f32x4*)yr;

    // depth-2 prefetch (non-temporal: zero-reuse streams, bypass L2 allocate)
    f32x4 xv = __builtin_nontemporal_load(&xp[lane]);
    f32x4 xn = __builtin_nontemporal_load(&xp[64 + lane]);

    for (int i = 0; i < NIT; ++i) {
        f32x4 xm = {0.f, 0.f, 0.f, 0.f};
        if (i + 2 < NIT)
            xm = __builtin_nontemporal_load(&xp[(size_t)(i + 2) * 64 + lane]);

        // ---- zero-start fold over 4 samples ----
        float d0 = c0 * xv[0];
        float d1 = c1 * xv[0];
        #define FOLD(xs)                                               \
        {   float t0 = fmaf(c0, (xs), fmaf(na1, d0, d1));              \
            float t1 = fmaf(na2, d0, c1 * (xs));                       \
            d0 = t0; d1 = t1; }
        FOLD(xv[1]) FOLD(xv[2]) FOLD(xv[3])
        #undef FOLD

        // ---- inclusive Hillis-Steele scan across lanes ----
        #define SCAN_STEP(Sm, o)                                        \
        {   float q0 = __shfl_up(d0, (unsigned)(o));                    \
            float q1 = __shfl_up(d1, (unsigned)(o));                    \
            if (lane < (o)) { q0 = 0.f; q1 = 0.f; }                     \
            float t0 = fmaf(Sm.a, q0, fmaf(Sm.b, q1, d0));              \
            float t1 = fmaf(Sm.c, q0, fmaf(Sm.d, q1, d1));              \
            d0 = t0; d1 = t1; }
        SCAN_STEP(S0, 1)
        SCAN_STEP(S1, 2)
        SCAN_STEP(S2, 4)
        SCAN_STEP(S3, 8)
        SCAN_STEP(S4, 16)
        SCAN_STEP(S5, 32)
        #undef SCAN_STEP

        // ---- exclusive shift ----
        float e0 = __shfl_up(d0, 1u);
        float e1 = __shfl_up(d1, 1u);
        if (lane == 0) { e0 = 0.f; e1 = 0.f; }

        // ---- per-lane segment start state ----
        float v0r = fmaf(Q.a, vc0, fmaf(Q.b, vc1, e0));
        float v1r = fmaf(Q.c, vc0, fmaf(Q.d, vc1, e1));

        // ---- replay 4 samples, emit y ----
        f32x4 yv;
        #define REPLAY(xs, dst)                                        \
        {   float yy = fmaf((xs), b0, v0r);                            \
            float n0 = fmaf(na1, yy, fmaf((xs), b1, v1r));             \
            float n1 = fmaf(na2, yy, (xs) * b2);                       \
            v0r = n0; v1r = n1; dst = yy; }
        REPLAY(xv[0], yv[0]) REPLAY(xv[1], yv[1])
        REPLAY(xv[2], yv[2]) REPLAY(xv[3], yv[3])
        #undef REPLAY

        __builtin_nontemporal_store(yv, &yp[(size_t)i * 64 + lane]);

        // ---- carry: v_carry = A^256 * v_carry + d_inclusive[63] ----
        float t0 = __shfl(d0, 63);
        float t1 = __shfl(d1, 63);
        float nv0 = fmaf(R.a, vc0, fmaf(R.b, vc1, t0));
        float nv1 = fmaf(R.c, vc0, fmaf(R.d, vc1, t1));
        vc0 = nv0; vc1 = nv1;

        xv = xn; xn = xm;
    }

    if (lane == 0) {
        vout[row * 2 + 0] = vc0;
        vout[row * 2 + 1] = vc1;
    }
}

extern "C" void kernel_launch(void* const* d_in, const int* in_sizes, int n_in,
                              void* d_out, int out_size, void* d_ws, size_t ws_size,
                              hipStream_t stream) {
    const float* x   = (const float*)d_in[0];
    const float* v0  = (const float*)d_in[1];
    const float* b0  = (const float*)d_in[2];
    const float* b1  = (const float*)d_in[3];
    const float* b2  = (const float*)d_in[4];
    const float* a1  = (const float*)d_in[5];
    const float* a2  = (const float*)d_in[6];

    float* y    = (float*)d_out;
    float* vout = (float*)d_out + (size_t)B_DIM * T_DIM;

    dim3 grid(B_DIM / WAVES_PER_BLOCK);
    dim3 block(64 * WAVES_PER_BLOCK);
    biquad_scan_kernel<<<grid, block, 0, stream>>>(x, v0, b0, b1, b2, a1, a2, y, vout);
}